// Round 3
// baseline (407.163 us; speedup 1.0000x reference)
//
#include <hip/hip_runtime.h>

// GraphSAGE 3-layer forward on MI355X.
// Pipeline per launch (all on `stream`, graph-capture-safe):
//  1. memset deg=0; histogram deg[dst]++ (int atomics)
//  2. two-level multi-block scan -> row_ptr (exclusive), cursor copy, deg_inv
//  3. counting-sort scatter -> edge_src (CSR by dst)
//  4. pull aggregation (atomic-free) + fused fp32 GEMM per layer

#define EMB 128
#define SCAN_CHUNK 1024  // elements per block in the scan (256 thr x 4)

// ---------------- CSR build ----------------

__global__ void count_deg_kernel(const int* __restrict__ dst, int* __restrict__ deg, int e) {
    int i = blockIdx.x * blockDim.x + threadIdx.x;
    if (i < e) atomicAdd(&deg[dst[i]], 1);
}

__device__ __forceinline__ int wave_incl_scan(int v, int lane) {
#pragma unroll
    for (int off = 1; off < 64; off <<= 1) {
        int u = __shfl_up(v, off);
        if (lane >= off) v += u;
    }
    return v;
}

// Kernel A: per-block sums of deg (SCAN_CHUNK elements/block)
__global__ __launch_bounds__(256) void partial_sum_kernel(const int* __restrict__ deg,
                                                          int* __restrict__ partials, int n) {
    const int t = threadIdx.x;
    const int base = blockIdx.x * SCAN_CHUNK + t * 4;
    int s = 0;
    if (base + 3 < n) {
        int4 v = *(const int4*)(deg + base);
        s = v.x + v.y + v.z + v.w;
    } else {
        for (int i = 0; i < 4; ++i)
            if (base + i < n) s += deg[base + i];
    }
    const int lane = t & 63, wid = t >> 6;
#pragma unroll
    for (int off = 32; off > 0; off >>= 1) s += __shfl_down(s, off);
    __shared__ int wsum[4];
    if (lane == 0) wsum[wid] = s;
    __syncthreads();
    if (t == 0) partials[blockIdx.x] = wsum[0] + wsum[1] + wsum[2] + wsum[3];
}

// Kernel B: single-block exclusive scan of the (<=256) partials; writes row_ptr[n]=E.
__global__ __launch_bounds__(256) void scan_partials_kernel(int* __restrict__ partials, int nb,
                                                            int* __restrict__ row_ptr, int n) {
    const int t = threadIdx.x;
    int v = (t < nb) ? partials[t] : 0;
    const int lane = t & 63, wid = t >> 6;
    int incl = wave_incl_scan(v, lane);
    __shared__ int wsum[4];
    if (lane == 63) wsum[wid] = incl;
    __syncthreads();
    int woff = 0;
    for (int w = 0; w < wid; ++w) woff += wsum[w];
    incl += woff;
    if (t < nb) partials[t] = incl - v;  // exclusive
    if (t == nb - 1) row_ptr[n] = incl;  // total edge count
}

// Kernel C: final scan — per-block exclusive scan + block offset; writes
// row_ptr, cursor, deg_inv.
__global__ __launch_bounds__(256) void scan_final_kernel(const int* __restrict__ deg,
                                                         const int* __restrict__ partials,
                                                         int* __restrict__ row_ptr,
                                                         int* __restrict__ cursor,
                                                         float* __restrict__ deg_inv, int n) {
    const int t = threadIdx.x;
    const int base = blockIdx.x * SCAN_CHUNK + t * 4;
    int d[4] = {0, 0, 0, 0};
    if (base + 3 < n) {
        int4 v = *(const int4*)(deg + base);
        d[0] = v.x; d[1] = v.y; d[2] = v.z; d[3] = v.w;
    } else {
        for (int i = 0; i < 4; ++i)
            if (base + i < n) d[i] = deg[base + i];
    }
    const int tsum = d[0] + d[1] + d[2] + d[3];
    const int lane = t & 63, wid = t >> 6;
    int incl = wave_incl_scan(tsum, lane);
    __shared__ int wsum[4];
    if (lane == 63) wsum[wid] = incl;
    __syncthreads();
    int off = partials[blockIdx.x];
    for (int w = 0; w < wid; ++w) off += wsum[w];
    int run = off + incl - tsum;  // exclusive prefix at this thread's first element
#pragma unroll
    for (int i = 0; i < 4; ++i) {
        int idx = base + i;
        if (idx < n) {
            row_ptr[idx] = run;
            cursor[idx] = run;
            deg_inv[idx] = (d[i] > 0) ? 1.0f / (float)d[i] : 0.0f;
            run += d[i];
        }
    }
}

__global__ void fill_csr_kernel(const int* __restrict__ src, const int* __restrict__ dst,
                                int* __restrict__ cursor, int* __restrict__ edge_src, int e) {
    int i = blockIdx.x * blockDim.x + threadIdx.x;
    if (i < e) {
        int p = atomicAdd(&cursor[dst[i]], 1);
        edge_src[p] = src[i];
    }
}

// ---------------- aggregation ----------------

// d_in = 8 (layer 1): one thread per node.
__global__ void agg8_kernel(const float* __restrict__ x, const int* __restrict__ row_ptr,
                            const int* __restrict__ edge_src, const float* __restrict__ deg_inv,
                            float* __restrict__ agg, int n) {
    int node = blockIdx.x * blockDim.x + threadIdx.x;
    if (node >= n) return;
    int s0 = row_ptr[node], s1 = row_ptr[node + 1];
    float a0 = 0.f, a1 = 0.f, a2 = 0.f, a3 = 0.f, a4 = 0.f, a5 = 0.f, a6 = 0.f, a7 = 0.f;
    for (int e = s0; e < s1; ++e) {
        int s = edge_src[e];
        const float4 v0 = *(const float4*)(x + (size_t)s * 8);
        const float4 v1 = *(const float4*)(x + (size_t)s * 8 + 4);
        a0 += v0.x; a1 += v0.y; a2 += v0.z; a3 += v0.w;
        a4 += v1.x; a5 += v1.y; a6 += v1.z; a7 += v1.w;
    }
    float di = deg_inv[node];
    float4 r0 = make_float4(a0 * di, a1 * di, a2 * di, a3 * di);
    float4 r1 = make_float4(a4 * di, a5 * di, a6 * di, a7 * di);
    *(float4*)(agg + (size_t)node * 8) = r0;
    *(float4*)(agg + (size_t)node * 8 + 4) = r1;
}

// d_in = 128: one wave per node, lane covers 2 channels (float2 -> 512B/edge
// coalesced). 4-wide edge unroll for memory-level parallelism.
__global__ __launch_bounds__(256) void agg128_kernel(const float* __restrict__ h,
                                                     const int* __restrict__ row_ptr,
                                                     const int* __restrict__ edge_src,
                                                     const float* __restrict__ deg_inv,
                                                     float* __restrict__ agg, int n) {
    const int wave = threadIdx.x >> 6;
    const int lane = threadIdx.x & 63;
    const int node = blockIdx.x * 4 + wave;
    if (node >= n) return;
    const int s0 = row_ptr[node];
    const int s1 = row_ptr[node + 1];
    float ax = 0.f, ay = 0.f;
    int e = s0;
    for (; e + 4 <= s1; e += 4) {
        const int sa = edge_src[e];
        const int sb = edge_src[e + 1];
        const int sc = edge_src[e + 2];
        const int sd = edge_src[e + 3];
        const float2 va = *(const float2*)(h + (size_t)sa * EMB + lane * 2);
        const float2 vb = *(const float2*)(h + (size_t)sb * EMB + lane * 2);
        const float2 vc = *(const float2*)(h + (size_t)sc * EMB + lane * 2);
        const float2 vd = *(const float2*)(h + (size_t)sd * EMB + lane * 2);
        ax += (va.x + vb.x) + (vc.x + vd.x);
        ay += (va.y + vb.y) + (vc.y + vd.y);
    }
    for (; e < s1; ++e) {
        const int sa = edge_src[e];
        const float2 va = *(const float2*)(h + (size_t)sa * EMB + lane * 2);
        ax += va.x;
        ay += va.y;
    }
    const float di = deg_inv[node];
    float2 r = make_float2(ax * di, ay * di);
    *(float2*)(agg + (size_t)node * EMB + lane * 2) = r;
}

// ---------------- fused GEMM: out = act(A@Wl + B@Wr + bias (+ B-row skip)) ----------------
// A,B: [n, K]; Wl,Wr: [K, 128]; out: [n, 128]
// Block: 256 threads, 32 rows. Thread (tx=t&15, ty=t>>4) owns cols tx*8..+7 and
// rows {ty, ty+16}. Per wave-k-step: 128 FMA insts vs 4 ds_read_b128 (LDS demand
// 1/16 per cyc < 1/12 supply) + 16 L2 weight loads. A/B tiles in LDS with an XOR
// swizzle on the f4 column (cf ^ (row&3)) so the 2x2 distinct rows a wave reads
// per b128 land in distinct bank groups (row stride 128 words === 0 mod 32 would
// otherwise 4-way conflict). Weights stay in L2 (128 KB, reused by all blocks).

template <int K, bool RELU, bool SKIP>
__global__ __launch_bounds__(256) void fused_gemm_kernel(const float* __restrict__ A,
                                                         const float* __restrict__ B,
                                                         const float* __restrict__ Wl,
                                                         const float* __restrict__ Wr,
                                                         const float* __restrict__ bias,
                                                         float* __restrict__ out, int n) {
    constexpr int KF = K / 4;        // float4s per row
    constexpr int SWM = KF - 1;      // swizzle mask (guards K=8)
    __shared__ float4 As[32 * KF];
    __shared__ float4 Bs[32 * KF];
    const int t = threadIdx.x;
    const int rb = blockIdx.x * 32;

    // stage A/B tiles (32 rows x K) with swizzled f4-column
    for (int j = t; j < 32 * KF; j += 256) {
        const int row = j / KF;
        const int cf = j % KF;
        const int r = rb + row;
        float4 va = make_float4(0.f, 0.f, 0.f, 0.f);
        float4 vb = va;
        if (r < n) {
            va = *(const float4*)(A + (size_t)r * K + cf * 4);
            vb = *(const float4*)(B + (size_t)r * K + cf * 4);
        }
        const int cfs = cf ^ (row & 3 & SWM);
        As[row * KF + cfs] = va;
        Bs[row * KF + cfs] = vb;
    }
    __syncthreads();

    const int tx = t & 15;
    const int ty = t >> 4;
    const int c0 = tx * 8;
    const int sw = ty & 3 & SWM;  // (ty+16)&3 == ty&3: same swizzle for both rows

    const float4 bv0 = *(const float4*)(bias + c0);
    const float4 bv1 = *(const float4*)(bias + c0 + 4);
    float4 acc[2][2] = {{bv0, bv1}, {bv0, bv1}};

#pragma unroll 2
    for (int k = 0; k < K; k += 4) {
        const int kf = k >> 2;
        const float4 a0 = As[ty * KF + (kf ^ sw)];
        const float4 a1 = As[(ty + 16) * KF + (kf ^ sw)];
        const float4 b0 = Bs[ty * KF + (kf ^ sw)];
        const float4 b1 = Bs[(ty + 16) * KF + (kf ^ sw)];
#pragma unroll
        for (int kk = 0; kk < 4; ++kk) {
            const float4 wl0 = *(const float4*)(Wl + (size_t)(k + kk) * EMB + c0);
            const float4 wl1 = *(const float4*)(Wl + (size_t)(k + kk) * EMB + c0 + 4);
            const float4 wr0 = *(const float4*)(Wr + (size_t)(k + kk) * EMB + c0);
            const float4 wr1 = *(const float4*)(Wr + (size_t)(k + kk) * EMB + c0 + 4);
            const float av0 = ((const float*)&a0)[kk];
            const float av1 = ((const float*)&a1)[kk];
            const float bw0 = ((const float*)&b0)[kk];
            const float bw1 = ((const float*)&b1)[kk];
            acc[0][0].x = fmaf(av0, wl0.x, acc[0][0].x);
            acc[0][0].y = fmaf(av0, wl0.y, acc[0][0].y);
            acc[0][0].z = fmaf(av0, wl0.z, acc[0][0].z);
            acc[0][0].w = fmaf(av0, wl0.w, acc[0][0].w);
            acc[0][1].x = fmaf(av0, wl1.x, acc[0][1].x);
            acc[0][1].y = fmaf(av0, wl1.y, acc[0][1].y);
            acc[0][1].z = fmaf(av0, wl1.z, acc[0][1].z);
            acc[0][1].w = fmaf(av0, wl1.w, acc[0][1].w);
            acc[0][0].x = fmaf(bw0, wr0.x, acc[0][0].x);
            acc[0][0].y = fmaf(bw0, wr0.y, acc[0][0].y);
            acc[0][0].z = fmaf(bw0, wr0.z, acc[0][0].z);
            acc[0][0].w = fmaf(bw0, wr0.w, acc[0][0].w);
            acc[0][1].x = fmaf(bw0, wr1.x, acc[0][1].x);
            acc[0][1].y = fmaf(bw0, wr1.y, acc[0][1].y);
            acc[0][1].z = fmaf(bw0, wr1.z, acc[0][1].z);
            acc[0][1].w = fmaf(bw0, wr1.w, acc[0][1].w);
            acc[1][0].x = fmaf(av1, wl0.x, acc[1][0].x);
            acc[1][0].y = fmaf(av1, wl0.y, acc[1][0].y);
            acc[1][0].z = fmaf(av1, wl0.z, acc[1][0].z);
            acc[1][0].w = fmaf(av1, wl0.w, acc[1][0].w);
            acc[1][1].x = fmaf(av1, wl1.x, acc[1][1].x);
            acc[1][1].y = fmaf(av1, wl1.y, acc[1][1].y);
            acc[1][1].z = fmaf(av1, wl1.z, acc[1][1].z);
            acc[1][1].w = fmaf(av1, wl1.w, acc[1][1].w);
            acc[1][0].x = fmaf(bw1, wr0.x, acc[1][0].x);
            acc[1][0].y = fmaf(bw1, wr0.y, acc[1][0].y);
            acc[1][0].z = fmaf(bw1, wr0.z, acc[1][0].z);
            acc[1][0].w = fmaf(bw1, wr0.w, acc[1][0].w);
            acc[1][1].x = fmaf(bw1, wr1.x, acc[1][1].x);
            acc[1][1].y = fmaf(bw1, wr1.y, acc[1][1].y);
            acc[1][1].z = fmaf(bw1, wr1.z, acc[1][1].z);
            acc[1][1].w = fmaf(bw1, wr1.w, acc[1][1].w);
        }
    }

#pragma unroll
    for (int i = 0; i < 2; ++i) {
        const int row = ty + 16 * i;
        const int r = rb + row;
        if (r < n) {
            float4 v0 = acc[i][0];
            float4 v1 = acc[i][1];
            if (SKIP) {
                const int cf = (K == EMB) ? (c0 >> 2) : 0;
                const float4 s0 = Bs[row * KF + ((cf) ^ sw)];
                const float4 s1 = Bs[row * KF + ((cf + (K == EMB ? 1 : 0)) ^ sw)];
                v0.x += s0.x; v0.y += s0.y; v0.z += s0.z; v0.w += s0.w;
                v1.x += s1.x; v1.y += s1.y; v1.z += s1.z; v1.w += s1.w;
            }
            if (RELU) {
                v0.x = fmaxf(v0.x, 0.f); v0.y = fmaxf(v0.y, 0.f);
                v0.z = fmaxf(v0.z, 0.f); v0.w = fmaxf(v0.w, 0.f);
                v1.x = fmaxf(v1.x, 0.f); v1.y = fmaxf(v1.y, 0.f);
                v1.z = fmaxf(v1.z, 0.f); v1.w = fmaxf(v1.w, 0.f);
            }
            *(float4*)(out + (size_t)r * EMB + c0) = v0;
            *(float4*)(out + (size_t)r * EMB + c0 + 4) = v1;
        }
    }
}

// ---------------- launcher ----------------

extern "C" void kernel_launch(void* const* d_in, const int* in_sizes, int n_in,
                              void* d_out, int out_size, void* d_ws, size_t ws_size,
                              hipStream_t stream) {
    const float* x   = (const float*)d_in[0];
    const int*   src = (const int*)d_in[1];
    const int*   dst = (const int*)d_in[2];
    const float* W1l = (const float*)d_in[3];
    const float* W1r = (const float*)d_in[4];
    const float* b1  = (const float*)d_in[5];
    const float* W2l = (const float*)d_in[6];
    const float* W2r = (const float*)d_in[7];
    const float* b2  = (const float*)d_in[8];
    const float* W3l = (const float*)d_in[9];
    const float* W3r = (const float*)d_in[10];
    const float* b3  = (const float*)d_in[11];
    float* out = (float*)d_out;

    const int N = in_sizes[0] / 8;
    const int E = in_sizes[1];

    // workspace layout (all 256B-aligned by construction)
    char* ws = (char*)d_ws;
    const size_t hbytes = (size_t)N * EMB * sizeof(float);  // 25,600,000
    float* h1  = (float*)ws;
    float* h2  = (float*)(ws + hbytes);
    float* agg = (float*)(ws + 2 * hbytes);
    int* deg      = (int*)(ws + 3 * hbytes);
    int* row_ptr  = deg + N;
    int* cursor   = row_ptr + N + 1;
    float* deg_inv = (float*)(cursor + N);
    int* edge_src = (int*)(deg_inv + N);
    int* partials = edge_src + E;

    const int nb = (N + SCAN_CHUNK - 1) / SCAN_CHUNK;  // 49 blocks

    // 1. degree histogram
    hipMemsetAsync(deg, 0, (size_t)N * sizeof(int), stream);
    count_deg_kernel<<<(E + 255) / 256, 256, 0, stream>>>(dst, deg, E);
    // 2. two-level scan -> row_ptr, cursor, deg_inv
    partial_sum_kernel<<<nb, 256, 0, stream>>>(deg, partials, N);
    scan_partials_kernel<<<1, 256, 0, stream>>>(partials, nb, row_ptr, N);
    scan_final_kernel<<<nb, 256, 0, stream>>>(deg, partials, row_ptr, cursor, deg_inv, N);
    // 3. scatter -> edge_src
    fill_csr_kernel<<<(E + 255) / 256, 256, 0, stream>>>(src, dst, cursor, edge_src, E);

    const int gemm_grid = (N + 31) / 32;
    const int agg_grid = (N + 3) / 4;

    // layer 1: h1 = relu(agg8(x)@W1l + x@W1r + b1)
    agg8_kernel<<<(N + 255) / 256, 256, 0, stream>>>(x, row_ptr, edge_src, deg_inv, agg, N);
    fused_gemm_kernel<8, true, false><<<gemm_grid, 256, 0, stream>>>(agg, x, W1l, W1r, b1, h1, N);

    // layer 2: h2 = relu(agg(h1)@W2l + h1@W2r + b2 + h1)
    agg128_kernel<<<agg_grid, 256, 0, stream>>>(h1, row_ptr, edge_src, deg_inv, agg, N);
    fused_gemm_kernel<128, true, true><<<gemm_grid, 256, 0, stream>>>(agg, h1, W2l, W2r, b2, h2, N);

    // layer 3: out = agg(h2)@W3l + h2@W3r + b3 + h2
    agg128_kernel<<<agg_grid, 256, 0, stream>>>(h2, row_ptr, edge_src, deg_inv, agg, N);
    fused_gemm_kernel<128, false, true><<<gemm_grid, 256, 0, stream>>>(agg, h2, W3l, W3r, b3, out, N);
}

// Round 4
// 218.039 us; speedup vs baseline: 1.8674x; 1.8674x over previous
//
#include <hip/hip_runtime.h>
#include <hip/hip_bf16.h>

// GraphSAGE 3-layer forward on MI355X.
//  - CSR build (histogram + two-level scan + scatter)
//  - layer 1 (K=8): fp32 VALU GEMM (4 rows x 4 cols / thread; round-2 structure)
//  - layers 2,3 (K=128+128): bf16 MFMA GEMM, stacked K=256, no LDS, no barriers
//  - aggregation: pull-based over CSR; layer-2/3 agg gathers bf16 (256 B/edge)

#define EMB 128
#define SCAN_CHUNK 1024

typedef __attribute__((ext_vector_type(8))) short short8v;   // 8 bf16 = 4 VGPRs
typedef __attribute__((ext_vector_type(4))) float f32x4;

static __device__ __forceinline__ float bfbits2f(unsigned short u) {
    unsigned int x = ((unsigned int)u) << 16;
    return __builtin_bit_cast(float, x);
}
static __device__ __forceinline__ unsigned short f2bfbits(float f) {
    __hip_bfloat16 h = __float2bfloat16(f);  // RTN
    return __builtin_bit_cast(unsigned short, h);
}

// ---------------- CSR build ----------------

__global__ void count_deg_kernel(const int* __restrict__ dst, int* __restrict__ deg, int e) {
    int i = blockIdx.x * blockDim.x + threadIdx.x;
    if (i < e) atomicAdd(&deg[dst[i]], 1);
}

__device__ __forceinline__ int wave_incl_scan(int v, int lane) {
#pragma unroll
    for (int off = 1; off < 64; off <<= 1) {
        int u = __shfl_up(v, off);
        if (lane >= off) v += u;
    }
    return v;
}

__global__ __launch_bounds__(256) void partial_sum_kernel(const int* __restrict__ deg,
                                                          int* __restrict__ partials, int n) {
    const int t = threadIdx.x;
    const int base = blockIdx.x * SCAN_CHUNK + t * 4;
    int s = 0;
    if (base + 3 < n) {
        int4 v = *(const int4*)(deg + base);
        s = v.x + v.y + v.z + v.w;
    } else {
        for (int i = 0; i < 4; ++i)
            if (base + i < n) s += deg[base + i];
    }
    const int lane = t & 63, wid = t >> 6;
#pragma unroll
    for (int off = 32; off > 0; off >>= 1) s += __shfl_down(s, off);
    __shared__ int wsum[4];
    if (lane == 0) wsum[wid] = s;
    __syncthreads();
    if (t == 0) partials[blockIdx.x] = wsum[0] + wsum[1] + wsum[2] + wsum[3];
}

__global__ __launch_bounds__(256) void scan_partials_kernel(int* __restrict__ partials, int nb,
                                                            int* __restrict__ row_ptr, int n) {
    const int t = threadIdx.x;
    int v = (t < nb) ? partials[t] : 0;
    const int lane = t & 63, wid = t >> 6;
    int incl = wave_incl_scan(v, lane);
    __shared__ int wsum[4];
    if (lane == 63) wsum[wid] = incl;
    __syncthreads();
    int woff = 0;
    for (int w = 0; w < wid; ++w) woff += wsum[w];
    incl += woff;
    if (t < nb) partials[t] = incl - v;
    if (t == nb - 1) row_ptr[n] = incl;
}

__global__ __launch_bounds__(256) void scan_final_kernel(const int* __restrict__ deg,
                                                         const int* __restrict__ partials,
                                                         int* __restrict__ row_ptr,
                                                         int* __restrict__ cursor,
                                                         float* __restrict__ deg_inv, int n) {
    const int t = threadIdx.x;
    const int base = blockIdx.x * SCAN_CHUNK + t * 4;
    int d[4] = {0, 0, 0, 0};
    if (base + 3 < n) {
        int4 v = *(const int4*)(deg + base);
        d[0] = v.x; d[1] = v.y; d[2] = v.z; d[3] = v.w;
    } else {
        for (int i = 0; i < 4; ++i)
            if (base + i < n) d[i] = deg[base + i];
    }
    const int tsum = d[0] + d[1] + d[2] + d[3];
    const int lane = t & 63, wid = t >> 6;
    int incl = wave_incl_scan(tsum, lane);
    __shared__ int wsum[4];
    if (lane == 63) wsum[wid] = incl;
    __syncthreads();
    int off = partials[blockIdx.x];
    for (int w = 0; w < wid; ++w) off += wsum[w];
    int run = off + incl - tsum;
#pragma unroll
    for (int i = 0; i < 4; ++i) {
        int idx = base + i;
        if (idx < n) {
            row_ptr[idx] = run;
            cursor[idx] = run;
            deg_inv[idx] = (d[i] > 0) ? 1.0f / (float)d[i] : 0.0f;
            run += d[i];
        }
    }
}

__global__ void fill_csr_kernel(const int* __restrict__ src, const int* __restrict__ dst,
                                int* __restrict__ cursor, int* __restrict__ edge_src, int e) {
    int i = blockIdx.x * blockDim.x + threadIdx.x;
    if (i < e) {
        int p = atomicAdd(&cursor[dst[i]], 1);
        edge_src[p] = src[i];
    }
}

// ---------------- aggregation ----------------

__global__ void agg8_kernel(const float* __restrict__ x, const int* __restrict__ row_ptr,
                            const int* __restrict__ edge_src, const float* __restrict__ deg_inv,
                            float* __restrict__ agg, int n) {
    int node = blockIdx.x * blockDim.x + threadIdx.x;
    if (node >= n) return;
    int s0 = row_ptr[node], s1 = row_ptr[node + 1];
    float a0 = 0.f, a1 = 0.f, a2 = 0.f, a3 = 0.f, a4 = 0.f, a5 = 0.f, a6 = 0.f, a7 = 0.f;
    for (int e = s0; e < s1; ++e) {
        int s = edge_src[e];
        const float4 v0 = *(const float4*)(x + (size_t)s * 8);
        const float4 v1 = *(const float4*)(x + (size_t)s * 8 + 4);
        a0 += v0.x; a1 += v0.y; a2 += v0.z; a3 += v0.w;
        a4 += v1.x; a5 += v1.y; a6 += v1.z; a7 += v1.w;
    }
    float di = deg_inv[node];
    *(float4*)(agg + (size_t)node * 8)     = make_float4(a0 * di, a1 * di, a2 * di, a3 * di);
    *(float4*)(agg + (size_t)node * 8 + 4) = make_float4(a4 * di, a5 * di, a6 * di, a7 * di);
}

// bf16 in / bf16 out; one wave per node, lane covers 2 channels (uint = 2 bf16).
__global__ __launch_bounds__(256) void agg128_bf16_kernel(const unsigned short* __restrict__ hb,
                                                          const int* __restrict__ row_ptr,
                                                          const int* __restrict__ edge_src,
                                                          const float* __restrict__ deg_inv,
                                                          unsigned short* __restrict__ aggb,
                                                          int n) {
    const int wave = threadIdx.x >> 6;
    const int lane = threadIdx.x & 63;
    const int node = blockIdx.x * 4 + wave;
    if (node >= n) return;
    const int s0 = row_ptr[node];
    const int s1 = row_ptr[node + 1];
    float ax = 0.f, ay = 0.f;
    int e = s0;
    for (; e + 4 <= s1; e += 4) {
        const int sa = edge_src[e];
        const int sb = edge_src[e + 1];
        const int sc = edge_src[e + 2];
        const int sd = edge_src[e + 3];
        const unsigned int va = *(const unsigned int*)(hb + (size_t)sa * EMB + lane * 2);
        const unsigned int vb = *(const unsigned int*)(hb + (size_t)sb * EMB + lane * 2);
        const unsigned int vc = *(const unsigned int*)(hb + (size_t)sc * EMB + lane * 2);
        const unsigned int vd = *(const unsigned int*)(hb + (size_t)sd * EMB + lane * 2);
        ax += (bfbits2f((unsigned short)va) + bfbits2f((unsigned short)vb)) +
              (bfbits2f((unsigned short)vc) + bfbits2f((unsigned short)vd));
        ay += (bfbits2f((unsigned short)(va >> 16)) + bfbits2f((unsigned short)(vb >> 16))) +
              (bfbits2f((unsigned short)(vc >> 16)) + bfbits2f((unsigned short)(vd >> 16)));
    }
    for (; e < s1; ++e) {
        const unsigned int va = *(const unsigned int*)(hb + (size_t)edge_src[e] * EMB + lane * 2);
        ax += bfbits2f((unsigned short)va);
        ay += bfbits2f((unsigned short)(va >> 16));
    }
    const float di = deg_inv[node];
    const unsigned int out = (unsigned int)f2bfbits(ax * di) |
                             ((unsigned int)f2bfbits(ay * di) << 16);
    *(unsigned int*)(aggb + (size_t)node * EMB + lane * 2) = out;
}

// ---------------- weight pack: Wp[s][ct][lane][i] = W[s*32+(l>>4)*8+i][ct*16+(l&15)] ----------------
// W = [Wl ; Wr] stacked along k (256 x 128). 4096 threads, each writes one 16 B frag.

__global__ __launch_bounds__(256) void pack_w_kernel(const float* __restrict__ Wl,
                                                     const float* __restrict__ Wr,
                                                     unsigned short* __restrict__ Wp) {
    const int t = blockIdx.x * blockDim.x + threadIdx.x;
    if (t >= 4096) return;
    const int s = t >> 9;
    const int ct = (t >> 6) & 7;
    const int l = t & 63;
    const int k0 = s * 32 + (l >> 4) * 8;
    const int c = ct * 16 + (l & 15);
    unsigned short frag[8];
#pragma unroll
    for (int i = 0; i < 8; ++i) {
        const int k = k0 + i;
        const float v = (k < 128) ? Wl[(size_t)k * EMB + c] : Wr[(size_t)(k - 128) * EMB + c];
        frag[i] = f2bfbits(v);
    }
    *(short8v*)(Wp + (size_t)t * 8) = *(const short8v*)frag;
}

// ---------------- MFMA GEMM: out = act([Ab|Hb] @ Wp + bias + skipf) ----------------
// 256 threads = 4 waves; block tile 64 rows x 128 cols; wave tile 16 rows x 128 cols.
// K = 256 in 8 steps of 32 (s<4 -> Ab, s>=4 -> Hb). No LDS, no barriers.
// A-frag: lane reads row rowbase+(l&15), k-offset (l>>4)*8 (16 B, same-kappa as Wp).
// C/D layout [m89]: col = ct*16 + (l&15), row = rowbase + (l>>4)*4 + reg.

template <bool RELU, bool WRITEB>
__global__ __launch_bounds__(256) void mfma_gemm_kernel(const unsigned short* __restrict__ Ab,
                                                        const unsigned short* __restrict__ Hb,
                                                        const unsigned short* __restrict__ Wp,
                                                        const float* __restrict__ bias,
                                                        const float* skipf,
                                                        float* outf,
                                                        unsigned short* __restrict__ outb,
                                                        int n) {
    const int l = threadIdx.x & 63;
    const int w = threadIdx.x >> 6;
    const int rowbase = blockIdx.x * 64 + w * 16;
    const int lr = l & 15;
    const int lg = l >> 4;

    int r0 = rowbase + lr;
    if (r0 > n - 1) r0 = n - 1;  // clamp: loads stay in-bounds, results discarded
    const size_t arow = (size_t)r0 * EMB + lg * 8;

    f32x4 acc[8] = {};

#pragma unroll
    for (int s = 0; s < 8; ++s) {
        const unsigned short* abase = (s < 4) ? (Ab + arow + s * 32)
                                              : (Hb + arow + (s - 4) * 32);
        const short8v af = *(const short8v*)abase;
        const unsigned short* wbase = Wp + ((size_t)(s * 8) * 64 + l) * 8;
#pragma unroll
        for (int ct = 0; ct < 8; ++ct) {
            const short8v bfr = *(const short8v*)(wbase + (size_t)ct * 64 * 8);
            acc[ct] = __builtin_amdgcn_mfma_f32_16x16x32_bf16(af, bfr, acc[ct], 0, 0, 0);
        }
    }

#pragma unroll
    for (int ct = 0; ct < 8; ++ct) {
        const int c = ct * 16 + lr;
        const float bv = bias[c];
#pragma unroll
        for (int j = 0; j < 4; ++j) {
            const int r = rowbase + lg * 4 + j;
            if (r < n) {
                float v = acc[ct][j] + bv + skipf[(size_t)r * EMB + c];
                if (RELU) v = fmaxf(v, 0.f);
                outf[(size_t)r * EMB + c] = v;
                if (WRITEB) outb[(size_t)r * EMB + c] = f2bfbits(v);
            }
        }
    }
}

// ---------------- layer-1 fp32 GEMM (K=8), round-2 structure + bf16 h write ----------------

template <int K, bool RELU>
__global__ __launch_bounds__(256) void fused_gemm_f32_kernel(const float* __restrict__ A,
                                                             const float* __restrict__ B,
                                                             const float* __restrict__ Wl,
                                                             const float* __restrict__ Wr,
                                                             const float* __restrict__ bias,
                                                             float* __restrict__ outf,
                                                             unsigned short* __restrict__ outb,
                                                             int n) {
    __shared__ float As[32][K];
    __shared__ float Bs[32][K];
    const int t = threadIdx.x;
    const int rb = blockIdx.x * 32;

    const int total4 = 32 * K / 4;
    for (int j = t; j < total4; j += 256) {
        int row = (j * 4) / K;
        int col = (j * 4) % K;
        int r = rb + row;
        float4 va = make_float4(0.f, 0.f, 0.f, 0.f);
        float4 vb = va;
        if (r < n) {
            va = *(const float4*)(A + (size_t)r * K + col);
            vb = *(const float4*)(B + (size_t)r * K + col);
        }
        *(float4*)&As[row][col] = va;
        *(float4*)&Bs[row][col] = vb;
    }
    __syncthreads();

    const int tx = t & 31;
    const int ty = t >> 5;
    const int c0 = tx * 4;

    const float4 bv = *(const float4*)(bias + c0);
    float4 acc[4] = {bv, bv, bv, bv};

#pragma unroll
    for (int k = 0; k < K; k += 4) {
        float4 a4[4], b4[4];
#pragma unroll
        for (int i = 0; i < 4; ++i) {
            a4[i] = *(const float4*)&As[ty + 8 * i][k];
            b4[i] = *(const float4*)&Bs[ty + 8 * i][k];
        }
#pragma unroll
        for (int kk = 0; kk < 4; ++kk) {
            const float4 wl = *(const float4*)(Wl + (size_t)(k + kk) * EMB + c0);
            const float4 wr = *(const float4*)(Wr + (size_t)(k + kk) * EMB + c0);
#pragma unroll
            for (int i = 0; i < 4; ++i) {
                const float av = ((const float*)&a4[i])[kk];
                const float bw = ((const float*)&b4[i])[kk];
                acc[i].x = fmaf(av, wl.x, acc[i].x);
                acc[i].y = fmaf(av, wl.y, acc[i].y);
                acc[i].z = fmaf(av, wl.z, acc[i].z);
                acc[i].w = fmaf(av, wl.w, acc[i].w);
                acc[i].x = fmaf(bw, wr.x, acc[i].x);
                acc[i].y = fmaf(bw, wr.y, acc[i].y);
                acc[i].z = fmaf(bw, wr.z, acc[i].z);
                acc[i].w = fmaf(bw, wr.w, acc[i].w);
            }
        }
    }

#pragma unroll
    for (int i = 0; i < 4; ++i) {
        int r = rb + ty + 8 * i;
        if (r < n) {
            float4 v = acc[i];
            if (RELU) {
                v.x = fmaxf(v.x, 0.f); v.y = fmaxf(v.y, 0.f);
                v.z = fmaxf(v.z, 0.f); v.w = fmaxf(v.w, 0.f);
            }
            *(float4*)(outf + (size_t)r * EMB + c0) = v;
            unsigned long long pk = (unsigned long long)f2bfbits(v.x) |
                                    ((unsigned long long)f2bfbits(v.y) << 16) |
                                    ((unsigned long long)f2bfbits(v.z) << 32) |
                                    ((unsigned long long)f2bfbits(v.w) << 48);
            *(unsigned long long*)(outb + (size_t)r * EMB + c0) = pk;
        }
    }
}

// ---------------- launcher ----------------

extern "C" void kernel_launch(void* const* d_in, const int* in_sizes, int n_in,
                              void* d_out, int out_size, void* d_ws, size_t ws_size,
                              hipStream_t stream) {
    const float* x   = (const float*)d_in[0];
    const int*   src = (const int*)d_in[1];
    const int*   dst = (const int*)d_in[2];
    const float* W1l = (const float*)d_in[3];
    const float* W1r = (const float*)d_in[4];
    const float* b1  = (const float*)d_in[5];
    const float* W2l = (const float*)d_in[6];
    const float* W2r = (const float*)d_in[7];
    const float* b2  = (const float*)d_in[8];
    const float* W3l = (const float*)d_in[9];
    const float* W3r = (const float*)d_in[10];
    const float* b3  = (const float*)d_in[11];
    float* out = (float*)d_out;

    const int N = in_sizes[0] / 8;
    const int E = in_sizes[1];

    // workspace layout (~69 MB; h2f aliases h1f: layer-2 epilogue reads skip
    // h1f[r][c] then writes h2f[r][c] in the same thread -> safe)
    char* ws = (char*)d_ws;
    const size_t hbytes  = (size_t)N * EMB * sizeof(float);           // 25.6 MB
    const size_t hbbytes = (size_t)N * EMB * sizeof(unsigned short);  // 12.8 MB
    float* h1f = (float*)ws;
    float* h2f = h1f;  // alias (see above)
    unsigned short* h1b  = (unsigned short*)(ws + hbytes);
    unsigned short* h2b  = (unsigned short*)(ws + hbytes + hbbytes);
    unsigned short* aggb = (unsigned short*)(ws + hbytes + 2 * hbbytes);
    float* agg8f = (float*)(ws + hbytes + 3 * hbbytes);               // N*8 f32
    char* p = ws + hbytes + 3 * hbbytes + (size_t)N * 8 * sizeof(float);
    unsigned short* Wp2 = (unsigned short*)p;  p += 4096 * 8 * sizeof(unsigned short);
    unsigned short* Wp3 = (unsigned short*)p;  p += 4096 * 8 * sizeof(unsigned short);
    int* deg      = (int*)p;
    int* row_ptr  = deg + N;
    int* cursor   = row_ptr + N + 1;
    float* deg_inv = (float*)(cursor + N);
    int* edge_src = (int*)(deg_inv + N);
    int* partials = edge_src + E;

    const int nb = (N + SCAN_CHUNK - 1) / SCAN_CHUNK;

    // CSR build
    hipMemsetAsync(deg, 0, (size_t)N * sizeof(int), stream);
    count_deg_kernel<<<(E + 255) / 256, 256, 0, stream>>>(dst, deg, E);
    partial_sum_kernel<<<nb, 256, 0, stream>>>(deg, partials, N);
    scan_partials_kernel<<<1, 256, 0, stream>>>(partials, nb, row_ptr, N);
    scan_final_kernel<<<nb, 256, 0, stream>>>(deg, partials, row_ptr, cursor, deg_inv, N);
    fill_csr_kernel<<<(E + 255) / 256, 256, 0, stream>>>(src, dst, cursor, edge_src, E);

    // weight packing for layers 2,3 (bf16, MFMA-fragment order)
    pack_w_kernel<<<16, 256, 0, stream>>>(W2l, W2r, Wp2);
    pack_w_kernel<<<16, 256, 0, stream>>>(W3l, W3r, Wp3);

    const int agg_grid  = (N + 3) / 4;
    const int mfma_grid = (N + 63) / 64;

    // layer 1: h1 = relu(agg8(x)@W1l + x@W1r + b1)  [fp32; writes h1f + h1b]
    agg8_kernel<<<(N + 255) / 256, 256, 0, stream>>>(x, row_ptr, edge_src, deg_inv, agg8f, N);
    fused_gemm_f32_kernel<8, true><<<(N + 31) / 32, 256, 0, stream>>>(
        agg8f, x, W1l, W1r, b1, h1f, h1b, N);

    // layer 2: h2 = relu([agg(h1)|h1]@[W2l;W2r] + b2 + h1)
    agg128_bf16_kernel<<<agg_grid, 256, 0, stream>>>(h1b, row_ptr, edge_src, deg_inv, aggb, N);
    mfma_gemm_kernel<true, true><<<mfma_grid, 256, 0, stream>>>(
        aggb, h1b, Wp2, b2, h1f /*skip*/, h2f, h2b, N);

    // layer 3: out = [agg(h2)|h2]@[W3l;W3r] + b3 + h2
    agg128_bf16_kernel<<<agg_grid, 256, 0, stream>>>(h2b, row_ptr, edge_src, deg_inv, aggb, N);
    mfma_gemm_kernel<false, false><<<mfma_grid, 256, 0, stream>>>(
        aggb, h2b, Wp3, b3, h2f /*skip*/, out, nullptr, N);
}

// Round 5
// 202.874 us; speedup vs baseline: 2.0070x; 1.0748x over previous
//
#include <hip/hip_runtime.h>
#include <hip/hip_bf16.h>

// GraphSAGE 3-layer forward on MI355X.
//  - CSR build (histogram + two-level scan + scatter), scan folded into 2 kernels
//  - layer 1 (K=8): fp32 VALU GEMM -> bf16 h1 only
//  - layers 2,3 (K=128+128): bf16 MFMA GEMM, stacked K=256, no LDS, no barriers
//  - aggregation: pull-based over CSR; 2 edges in flight per wave (uint2 lanes)

#define EMB 128
#define SCAN_CHUNK 1024

typedef __attribute__((ext_vector_type(8))) short short8v;   // 8 bf16 = 4 VGPRs
typedef __attribute__((ext_vector_type(4))) float f32x4;

static __device__ __forceinline__ float bfbits2f(unsigned short u) {
    unsigned int x = ((unsigned int)u) << 16;
    return __builtin_bit_cast(float, x);
}
static __device__ __forceinline__ unsigned short f2bfbits(float f) {
    __hip_bfloat16 h = __float2bfloat16(f);  // RTN
    return __builtin_bit_cast(unsigned short, h);
}

// ---------------- CSR build ----------------

__global__ void count_deg_kernel(const int* __restrict__ dst, int* __restrict__ deg, int e) {
    int i = blockIdx.x * blockDim.x + threadIdx.x;
    if (i < e) atomicAdd(&deg[dst[i]], 1);
}

__device__ __forceinline__ int wave_incl_scan(int v, int lane) {
#pragma unroll
    for (int off = 1; off < 64; off <<= 1) {
        int u = __shfl_up(v, off);
        if (lane >= off) v += u;
    }
    return v;
}

__global__ __launch_bounds__(256) void partial_sum_kernel(const int* __restrict__ deg,
                                                          int* __restrict__ partials, int n) {
    const int t = threadIdx.x;
    const int base = blockIdx.x * SCAN_CHUNK + t * 4;
    int s = 0;
    if (base + 3 < n) {
        int4 v = *(const int4*)(deg + base);
        s = v.x + v.y + v.z + v.w;
    } else {
        for (int i = 0; i < 4; ++i)
            if (base + i < n) s += deg[base + i];
    }
    const int lane = t & 63, wid = t >> 6;
#pragma unroll
    for (int off = 32; off > 0; off >>= 1) s += __shfl_down(s, off);
    __shared__ int wsum[4];
    if (lane == 0) wsum[wid] = s;
    __syncthreads();
    if (t == 0) partials[blockIdx.x] = wsum[0] + wsum[1] + wsum[2] + wsum[3];
}

// Final scan: each block redundantly wave-scans the (<=64) partials for its own
// offset (nb = ceil(N/1024) = 49 here), then per-block scan writes row_ptr,
// cursor, deg_inv. Block 0 also writes row_ptr[n] = E.
__global__ __launch_bounds__(256) void scan_final_kernel(const int* __restrict__ deg,
                                                         const int* __restrict__ partials,
                                                         int* __restrict__ row_ptr,
                                                         int* __restrict__ cursor,
                                                         float* __restrict__ deg_inv,
                                                         int n, int nb) {
    const int t = threadIdx.x;
    const int base = blockIdx.x * SCAN_CHUNK + t * 4;
    int d[4] = {0, 0, 0, 0};
    if (base + 3 < n) {
        int4 v = *(const int4*)(deg + base);
        d[0] = v.x; d[1] = v.y; d[2] = v.z; d[3] = v.w;
    } else {
        for (int i = 0; i < 4; ++i)
            if (base + i < n) d[i] = deg[base + i];
    }
    const int tsum = d[0] + d[1] + d[2] + d[3];
    const int lane = t & 63, wid = t >> 6;
    int incl = wave_incl_scan(tsum, lane);
    __shared__ int wsum[4];
    __shared__ int s_blkoff, s_total;
    if (lane == 63) wsum[wid] = incl;
    if (t < 64) {  // wave 0: scan the partials (requires nb <= 64)
        int v = (t < nb) ? partials[t] : 0;
        int pincl = wave_incl_scan(v, t);
        if (t == (int)blockIdx.x) s_blkoff = pincl - v;
        if (t == nb - 1) s_total = pincl;
    }
    __syncthreads();
    int off = s_blkoff;
    for (int w = 0; w < wid; ++w) off += wsum[w];
    int run = off + incl - tsum;
#pragma unroll
    for (int i = 0; i < 4; ++i) {
        int idx = base + i;
        if (idx < n) {
            row_ptr[idx] = run;
            cursor[idx] = run;
            deg_inv[idx] = (d[i] > 0) ? 1.0f / (float)d[i] : 0.0f;
            run += d[i];
        }
    }
    if (blockIdx.x == 0 && t == 0) row_ptr[n] = s_total;
}

__global__ void fill_csr_kernel(const int* __restrict__ src, const int* __restrict__ dst,
                                int* __restrict__ cursor, int* __restrict__ edge_src, int e) {
    int i = blockIdx.x * blockDim.x + threadIdx.x;
    if (i < e) {
        int p = atomicAdd(&cursor[dst[i]], 1);
        edge_src[p] = src[i];
    }
}

// ---------------- aggregation ----------------

// layer-1 agg (d=8): 8 lanes per node, one channel each; coalesced 32B row reads.
__global__ __launch_bounds__(256) void agg8_kernel(const float* __restrict__ x,
                                                   const int* __restrict__ row_ptr,
                                                   const int* __restrict__ edge_src,
                                                   const float* __restrict__ deg_inv,
                                                   float* __restrict__ agg, int n) {
    const int g = blockIdx.x * blockDim.x + threadIdx.x;
    const int node = g >> 3;
    const int ch = g & 7;
    if (node >= n) return;
    const int s0 = row_ptr[node], s1 = row_ptr[node + 1];
    float a = 0.f, b = 0.f;
    int e = s0;
    for (; e + 1 < s1; e += 2) {
        const int sa = edge_src[e];
        const int sb = edge_src[e + 1];
        a += x[(size_t)sa * 8 + ch];
        b += x[(size_t)sb * 8 + ch];
    }
    if (e < s1) a += x[(size_t)edge_src[e] * 8 + ch];
    agg[(size_t)node * 8 + ch] = (a + b) * deg_inv[node];
}

// layer-2/3 agg (d=128, bf16): one wave per node; 32 lanes cover a row (uint2 =
// 4 channels/lane), the two half-waves process alternating edges -> 2 edges
// concurrently, x4 unroll = 8 gathers in flight. Cross-half combine via shfl_xor.
__global__ __launch_bounds__(256) void agg128_bf16_kernel(const unsigned short* __restrict__ hb,
                                                          const int* __restrict__ row_ptr,
                                                          const int* __restrict__ edge_src,
                                                          const float* __restrict__ deg_inv,
                                                          unsigned short* __restrict__ aggb,
                                                          int n) {
    const int wave = threadIdx.x >> 6;
    const int lane = threadIdx.x & 63;
    const int half = lane >> 5;   // which edge of the pair
    const int cl = lane & 31;     // channel group: channels 4*cl..4*cl+3
    const int node = blockIdx.x * 4 + wave;
    if (node >= n) return;
    const int s0 = row_ptr[node];
    const int s1 = row_ptr[node + 1];
    const size_t coff = (size_t)cl * 4;
    float a0 = 0.f, a1 = 0.f, a2 = 0.f, a3 = 0.f;
    int e = s0 + half;
    for (; e + 6 < s1; e += 8) {
        const int sa = edge_src[e];
        const int sb = edge_src[e + 2];
        const int sc = edge_src[e + 4];
        const int sd = edge_src[e + 6];
        const uint2 va = *(const uint2*)(hb + (size_t)sa * EMB + coff);
        const uint2 vb = *(const uint2*)(hb + (size_t)sb * EMB + coff);
        const uint2 vc = *(const uint2*)(hb + (size_t)sc * EMB + coff);
        const uint2 vd = *(const uint2*)(hb + (size_t)sd * EMB + coff);
        a0 += (bfbits2f((unsigned short)va.x) + bfbits2f((unsigned short)vb.x)) +
              (bfbits2f((unsigned short)vc.x) + bfbits2f((unsigned short)vd.x));
        a1 += (bfbits2f((unsigned short)(va.x >> 16)) + bfbits2f((unsigned short)(vb.x >> 16))) +
              (bfbits2f((unsigned short)(vc.x >> 16)) + bfbits2f((unsigned short)(vd.x >> 16)));
        a2 += (bfbits2f((unsigned short)va.y) + bfbits2f((unsigned short)vb.y)) +
              (bfbits2f((unsigned short)vc.y) + bfbits2f((unsigned short)vd.y));
        a3 += (bfbits2f((unsigned short)(va.y >> 16)) + bfbits2f((unsigned short)(vb.y >> 16))) +
              (bfbits2f((unsigned short)(vc.y >> 16)) + bfbits2f((unsigned short)(vd.y >> 16)));
    }
    for (; e < s1; e += 2) {
        const uint2 v = *(const uint2*)(hb + (size_t)edge_src[e] * EMB + coff);
        a0 += bfbits2f((unsigned short)v.x);
        a1 += bfbits2f((unsigned short)(v.x >> 16));
        a2 += bfbits2f((unsigned short)v.y);
        a3 += bfbits2f((unsigned short)(v.y >> 16));
    }
    a0 += __shfl_xor(a0, 32);
    a1 += __shfl_xor(a1, 32);
    a2 += __shfl_xor(a2, 32);
    a3 += __shfl_xor(a3, 32);
    if (half == 0) {
        const float di = deg_inv[node];
        uint2 o;
        o.x = (unsigned int)f2bfbits(a0 * di) | ((unsigned int)f2bfbits(a1 * di) << 16);
        o.y = (unsigned int)f2bfbits(a2 * di) | ((unsigned int)f2bfbits(a3 * di) << 16);
        *(uint2*)(aggb + (size_t)node * EMB + coff) = o;
    }
}

// ---------------- weight pack (both layers in one kernel) ----------------
// Wp[s][ct][lane][i] = W[s*32+(l>>4)*8+i][ct*16+(l&15)], W = [Wl;Wr] (256x128).

__global__ __launch_bounds__(256) void pack_w_kernel(const float* __restrict__ W2l,
                                                     const float* __restrict__ W2r,
                                                     const float* __restrict__ W3l,
                                                     const float* __restrict__ W3r,
                                                     unsigned short* __restrict__ Wp2,
                                                     unsigned short* __restrict__ Wp3) {
    int t = blockIdx.x * blockDim.x + threadIdx.x;  // 0..8191
    const bool second = t >= 4096;
    const float* Wl = second ? W3l : W2l;
    const float* Wr = second ? W3r : W2r;
    unsigned short* Wp = second ? Wp3 : Wp2;
    t &= 4095;
    const int s = t >> 9;
    const int ct = (t >> 6) & 7;
    const int l = t & 63;
    const int k0 = s * 32 + (l >> 4) * 8;
    const int c = ct * 16 + (l & 15);
    unsigned short frag[8];
#pragma unroll
    for (int i = 0; i < 8; ++i) {
        const int k = k0 + i;
        const float v = (k < 128) ? Wl[(size_t)k * EMB + c] : Wr[(size_t)(k - 128) * EMB + c];
        frag[i] = f2bfbits(v);
    }
    *(short8v*)(Wp + (size_t)t * 8) = *(const short8v*)frag;
}

// ---------------- MFMA GEMM: out = act([Ab|Hb] @ Wp + bias + skip) ----------------
// 256 threads = 4 waves; block tile 64 rows; K=256 in 8 steps of 32.
// C/D layout [m89]: col = ct*16 + (l&15), row = rowbase + (l>>4)*4 + reg.

template <bool RELU, bool WRITEB, bool SKIPB>
__global__ __launch_bounds__(256) void mfma_gemm_kernel(const unsigned short* __restrict__ Ab,
                                                        const unsigned short* __restrict__ Hb,
                                                        const unsigned short* __restrict__ Wp,
                                                        const float* __restrict__ bias,
                                                        const float* skipf,
                                                        const unsigned short* skipb,
                                                        float* outf,
                                                        unsigned short* __restrict__ outb,
                                                        int n) {
    const int l = threadIdx.x & 63;
    const int w = threadIdx.x >> 6;
    const int rowbase = blockIdx.x * 64 + w * 16;
    const int lr = l & 15;
    const int lg = l >> 4;

    int r0 = rowbase + lr;
    if (r0 > n - 1) r0 = n - 1;  // clamp: loads in-bounds, results discarded
    const size_t arow = (size_t)r0 * EMB + lg * 8;

    f32x4 acc[8] = {};

#pragma unroll
    for (int s = 0; s < 8; ++s) {
        const unsigned short* abase = (s < 4) ? (Ab + arow + s * 32)
                                              : (Hb + arow + (s - 4) * 32);
        const short8v af = *(const short8v*)abase;
        const unsigned short* wbase = Wp + ((size_t)(s * 8) * 64 + l) * 8;
#pragma unroll
        for (int ct = 0; ct < 8; ++ct) {
            const short8v bfr = *(const short8v*)(wbase + (size_t)ct * 64 * 8);
            acc[ct] = __builtin_amdgcn_mfma_f32_16x16x32_bf16(af, bfr, acc[ct], 0, 0, 0);
        }
    }

#pragma unroll
    for (int ct = 0; ct < 8; ++ct) {
        const int c = ct * 16 + lr;
        const float bv = bias[c];
#pragma unroll
        for (int j = 0; j < 4; ++j) {
            const int r = rowbase + lg * 4 + j;
            if (r < n) {
                const float sk = SKIPB ? bfbits2f(skipb[(size_t)r * EMB + c])
                                       : skipf[(size_t)r * EMB + c];
                float v = acc[ct][j] + bv + sk;
                if (RELU) v = fmaxf(v, 0.f);
                outf[(size_t)r * EMB + c] = v;
                if (WRITEB) outb[(size_t)r * EMB + c] = f2bfbits(v);
            }
        }
    }
}

// ---------------- layer-1 fp32 GEMM (K=8) -> bf16 h1 only ----------------

template <int K, bool RELU>
__global__ __launch_bounds__(256) void fused_gemm_f32_kernel(const float* __restrict__ A,
                                                             const float* __restrict__ B,
                                                             const float* __restrict__ Wl,
                                                             const float* __restrict__ Wr,
                                                             const float* __restrict__ bias,
                                                             unsigned short* __restrict__ outb,
                                                             int n) {
    __shared__ float As[32][K];
    __shared__ float Bs[32][K];
    const int t = threadIdx.x;
    const int rb = blockIdx.x * 32;

    const int total4 = 32 * K / 4;
    for (int j = t; j < total4; j += 256) {
        int row = (j * 4) / K;
        int col = (j * 4) % K;
        int r = rb + row;
        float4 va = make_float4(0.f, 0.f, 0.f, 0.f);
        float4 vb = va;
        if (r < n) {
            va = *(const float4*)(A + (size_t)r * K + col);
            vb = *(const float4*)(B + (size_t)r * K + col);
        }
        *(float4*)&As[row][col] = va;
        *(float4*)&Bs[row][col] = vb;
    }
    __syncthreads();

    const int tx = t & 31;
    const int ty = t >> 5;
    const int c0 = tx * 4;

    const float4 bv = *(const float4*)(bias + c0);
    float4 acc[4] = {bv, bv, bv, bv};

#pragma unroll
    for (int k = 0; k < K; k += 4) {
        float4 a4[4], b4[4];
#pragma unroll
        for (int i = 0; i < 4; ++i) {
            a4[i] = *(const float4*)&As[ty + 8 * i][k];
            b4[i] = *(const float4*)&Bs[ty + 8 * i][k];
        }
#pragma unroll
        for (int kk = 0; kk < 4; ++kk) {
            const float4 wl = *(const float4*)(Wl + (size_t)(k + kk) * EMB + c0);
            const float4 wr = *(const float4*)(Wr + (size_t)(k + kk) * EMB + c0);
#pragma unroll
            for (int i = 0; i < 4; ++i) {
                const float av = ((const float*)&a4[i])[kk];
                const float bw = ((const float*)&b4[i])[kk];
                acc[i].x = fmaf(av, wl.x, acc[i].x);
                acc[i].y = fmaf(av, wl.y, acc[i].y);
                acc[i].z = fmaf(av, wl.z, acc[i].z);
                acc[i].w = fmaf(av, wl.w, acc[i].w);
                acc[i].x = fmaf(bw, wr.x, acc[i].x);
                acc[i].y = fmaf(bw, wr.y, acc[i].y);
                acc[i].z = fmaf(bw, wr.z, acc[i].z);
                acc[i].w = fmaf(bw, wr.w, acc[i].w);
            }
        }
    }

#pragma unroll
    for (int i = 0; i < 4; ++i) {
        int r = rb + ty + 8 * i;
        if (r < n) {
            float4 v = acc[i];
            if (RELU) {
                v.x = fmaxf(v.x, 0.f); v.y = fmaxf(v.y, 0.f);
                v.z = fmaxf(v.z, 0.f); v.w = fmaxf(v.w, 0.f);
            }
            unsigned long long pk = (unsigned long long)f2bfbits(v.x) |
                                    ((unsigned long long)f2bfbits(v.y) << 16) |
                                    ((unsigned long long)f2bfbits(v.z) << 32) |
                                    ((unsigned long long)f2bfbits(v.w) << 48);
            *(unsigned long long*)(outb + (size_t)r * EMB + c0) = pk;
        }
    }
}

// ---------------- launcher ----------------

extern "C" void kernel_launch(void* const* d_in, const int* in_sizes, int n_in,
                              void* d_out, int out_size, void* d_ws, size_t ws_size,
                              hipStream_t stream) {
    const float* x   = (const float*)d_in[0];
    const int*   src = (const int*)d_in[1];
    const int*   dst = (const int*)d_in[2];
    const float* W1l = (const float*)d_in[3];
    const float* W1r = (const float*)d_in[4];
    const float* b1  = (const float*)d_in[5];
    const float* W2l = (const float*)d_in[6];
    const float* W2r = (const float*)d_in[7];
    const float* b2  = (const float*)d_in[8];
    const float* W3l = (const float*)d_in[9];
    const float* W3r = (const float*)d_in[10];
    const float* b3  = (const float*)d_in[11];
    float* out = (float*)d_out;

    const int N = in_sizes[0] / 8;
    const int E = in_sizes[1];

    // workspace layout (~68 MB)
    char* ws = (char*)d_ws;
    const size_t hbytes  = (size_t)N * EMB * sizeof(float);           // 25.6 MB
    const size_t hbbytes = (size_t)N * EMB * sizeof(unsigned short);  // 12.8 MB
    float* h2f = (float*)ws;
    unsigned short* h1b  = (unsigned short*)(ws + hbytes);
    unsigned short* h2b  = (unsigned short*)(ws + hbytes + hbbytes);
    unsigned short* aggb = (unsigned short*)(ws + hbytes + 2 * hbbytes);
    float* agg8f = (float*)(ws + hbytes + 3 * hbbytes);               // N*8 f32
    char* p = ws + hbytes + 3 * hbbytes + (size_t)N * 8 * sizeof(float);
    unsigned short* Wp2 = (unsigned short*)p;  p += 4096 * 8 * sizeof(unsigned short);
    unsigned short* Wp3 = (unsigned short*)p;  p += 4096 * 8 * sizeof(unsigned short);
    int* deg      = (int*)p;
    int* row_ptr  = deg + N;
    int* cursor   = row_ptr + N + 1;
    float* deg_inv = (float*)(cursor + N);
    int* edge_src = (int*)(deg_inv + N);
    int* partials = edge_src + E;

    const int nb = (N + SCAN_CHUNK - 1) / SCAN_CHUNK;  // 49 (must be <= 64)

    // CSR build
    hipMemsetAsync(deg, 0, (size_t)N * sizeof(int), stream);
    count_deg_kernel<<<(E + 255) / 256, 256, 0, stream>>>(dst, deg, E);
    partial_sum_kernel<<<nb, 256, 0, stream>>>(deg, partials, N);
    scan_final_kernel<<<nb, 256, 0, stream>>>(deg, partials, row_ptr, cursor, deg_inv, N, nb);
    fill_csr_kernel<<<(E + 255) / 256, 256, 0, stream>>>(src, dst, cursor, edge_src, E);

    // weight packing for layers 2,3 (bf16, MFMA-fragment order)
    pack_w_kernel<<<32, 256, 0, stream>>>(W2l, W2r, W3l, W3r, Wp2, Wp3);

    const int agg_grid  = (N + 3) / 4;
    const int mfma_grid = (N + 63) / 64;

    // layer 1: h1 = relu(agg8(x)@W1l + x@W1r + b1)  [fp32 math, bf16 h1]
    agg8_kernel<<<(N * 8 + 255) / 256, 256, 0, stream>>>(x, row_ptr, edge_src, deg_inv, agg8f, N);
    fused_gemm_f32_kernel<8, true><<<(N + 31) / 32, 256, 0, stream>>>(
        agg8f, x, W1l, W1r, b1, h1b, N);

    // layer 2: h2 = relu([agg(h1)|h1]@[W2l;W2r] + b2 + h1)   [skip from bf16 h1]
    agg128_bf16_kernel<<<agg_grid, 256, 0, stream>>>(h1b, row_ptr, edge_src, deg_inv, aggb, N);
    mfma_gemm_kernel<true, true, true><<<mfma_grid, 256, 0, stream>>>(
        aggb, h1b, Wp2, b2, nullptr, h1b /*skip bf16*/, h2f, h2b, N);

    // layer 3: out = [agg(h2)|h2]@[W3l;W3r] + b3 + h2        [skip from fp32 h2]
    agg128_bf16_kernel<<<agg_grid, 256, 0, stream>>>(h2b, row_ptr, edge_src, deg_inv, aggb, N);
    mfma_gemm_kernel<false, false, false><<<mfma_grid, 256, 0, stream>>>(
        aggb, h2b, Wp3, b3, h2f /*skip f32*/, nullptr, out, nullptr, N);
}